// Round 17
// baseline (2138.400 us; speedup 1.0000x reference)
//
#include <hip/hip_runtime.h>

#define NROWS 1568      // BATCH * L = 8 * 196
#define MPAD  1600      // padded rows for GEMM tiles
#define LSEQ  196
#define EPS   1e-5f
#define TCH   7
#define NCH   28

typedef __attribute__((ext_vector_type(8))) short short8_t;   // 8 bf16
typedef __attribute__((ext_vector_type(8))) unsigned short ush8;
typedef __attribute__((ext_vector_type(4))) float f32x4;
typedef unsigned short ush;

__device__ __forceinline__ float silu_(float x) { return x / (1.f + expf(-x)); }

__device__ __forceinline__ ush bfh_(float f) {
  unsigned u = __float_as_uint(f);
  return (ush)((u + 0x7FFFu + ((u >> 16) & 1u)) >> 16);
}
__device__ __forceinline__ float bf2f_(ush h) {
  return __uint_as_float(((unsigned)h) << 16);
}

// async global->LDS, 16B per lane; LDS dest = wave-uniform base + lane*16
__device__ __forceinline__ void glds16(const ush* g, ush* l) {
  __builtin_amdgcn_global_load_lds(
      (const __attribute__((address_space(1))) void*)g,
      (__attribute__((address_space(3))) void*)l, 16, 0, 0);
}

// ---------------- merged weight split: patch_w | in_proj_w | out_proj_w ----------------
#define N8_PW  18432
#define N8_IPW 442368
#define N8_OPW 221184
__global__ __launch_bounds__(256) void wsplit3_k(const float* __restrict__ pw,
                                                 const float* __restrict__ ipw,
                                                 const float* __restrict__ opw,
                                                 ush* __restrict__ pw_h, ush* __restrict__ pw_l,
                                                 ush* __restrict__ ipw_h, ush* __restrict__ ipw_l,
                                                 ush* __restrict__ opw_h, ush* __restrict__ opw_l) {
  int i = blockIdx.x * 256 + threadIdx.x;
  const float* src;
  ush *hi, *lo;
  size_t off;
  if (i < N8_PW) { src = pw; hi = pw_h; lo = pw_l; off = i; }
  else if (i < N8_PW + N8_IPW) { src = ipw; hi = ipw_h; lo = ipw_l; off = i - N8_PW; }
  else if (i < N8_PW + N8_IPW + N8_OPW) { src = opw; hi = opw_h; lo = opw_l; off = i - N8_PW - N8_IPW; }
  else return;
  float v[8];
  *(float4*)&v[0] = *(const float4*)(src + off * 8);
  *(float4*)&v[4] = *(const float4*)(src + off * 8 + 4);
  ush8 h8, l8;
#pragma unroll
  for (int j = 0; j < 8; ++j) {
    ush h = bfh_(v[j]);
    h8[j] = h;
    l8[j] = bfh_(v[j] - bf2f_(h));
  }
  *(ush8*)&hi[off * 8] = h8;
  *(ush8*)&lo[off * 8] = l8;
}

// ---------------- zero res + pad rows of bf16 activation buffers ----------------
__global__ __launch_bounds__(256) void zeros_k(float* __restrict__ res,
                                               ush* __restrict__ a_h, ush* __restrict__ a_l,
                                               ush* __restrict__ hn_h, ush* __restrict__ hn_l,
                                               ush* __restrict__ y_h, ush* __restrict__ y_l) {
  int i = blockIdx.x * 256 + threadIdx.x;
  ush8 z = {};
  if (i < 75264) ((float4*)res)[i] = float4{0.f, 0.f, 0.f, 0.f};
  if (i < 3072) {
    ((ush8*)(a_h + (size_t)NROWS * 768))[i] = z;
    ((ush8*)(a_l + (size_t)NROWS * 768))[i] = z;
  }
  if (i < 768) {
    ((ush8*)(hn_h + (size_t)NROWS * 192))[i] = z;
    ((ush8*)(hn_l + (size_t)NROWS * 192))[i] = z;
  }
  if (i < 1536) {
    ((ush8*)(y_h + (size_t)NROWS * 384))[i] = z;
    ((ush8*)(y_l + (size_t)NROWS * 384))[i] = z;
  }
}

// ---------------- im2col for patch embedding, bf16 hi/lo out ----------------
__global__ __launch_bounds__(256) void im2col_k(const float* __restrict__ x,
                                                ush* __restrict__ Ah,
                                                ush* __restrict__ Al) {
  int i8 = blockIdx.x * 256 + threadIdx.x;
  if (i8 >= NROWS * 768 / 8) return;
  int idx = i8 * 8;
  int m = idx / 768, r = idx - m * 768;
  int b = m / LSEQ, l = m - b * LSEQ;
  int ph = l / 14, pw = l - ph * 14;
  int c = r >> 8, rem = r & 255, ii = rem >> 4, j = rem & 15;
  const float* src = &x[((b * 3 + c) * 224 + ph * 16 + ii) * 224 + pw * 16 + j];
  float v[8];
  *(float4*)&v[0] = *(const float4*)&src[0];
  *(float4*)&v[4] = *(const float4*)&src[4];
  ush8 h8, l8;
#pragma unroll
  for (int k = 0; k < 8; ++k) {
    ush h = bfh_(v[k]);
    h8[k] = h;
    l8[k] = bfh_(v[k] - bf2f_(h));
  }
  *(ush8*)&Ah[idx] = h8;
  *(ush8*)&Al[idx] = l8;
}

// ---------------- 64x64 MFMA GEMM: tri-buffered glds16, with reps ----------------
__global__ __launch_bounds__(256) void gemm64g_k(const ush* __restrict__ Ah_g,
                                                 const ush* __restrict__ Al_g,
                                                 const ush* __restrict__ Wh_g,
                                                 const ush* __restrict__ Wl_g,
                                                 const float* __restrict__ bias,
                                                 float* __restrict__ C, int N, int K,
                                                 int reps) {
  __shared__ ush sAh[3][2048], sAl[3][2048], sWh[3][2048], sWl[3][2048];
  const int tid = threadIdx.x, lane = tid & 63, wave = tid >> 6;
  const int ntiles = N / 64;
  const int row0 = (blockIdx.x / ntiles) * 64, col0 = (blockIdx.x % ntiles) * 64;
  const int sr = wave * 16 + (lane >> 2);
  const int j8 = ((lane & 3) ^ ((sr >> 1) & 3)) * 8;
  const size_t gaA = (size_t)(row0 + sr) * K + j8;
  const size_t gaW = (size_t)(col0 + sr) * K + j8;
  const int lb = wave * 512;
  const int nsteps = K >> 5;
  const int fr = lane & 15, fg = lane >> 4;
  const int wm = (wave & 1) * 32, wn = (wave >> 1) * 32;
  f32x4 acc[2][2];

  for (int rp = 0; rp < reps; ++rp) {
    asm volatile("" ::: "memory");
#pragma unroll
    for (int i = 0; i < 2; ++i)
#pragma unroll
      for (int j = 0; j < 2; ++j) acc[i][j] = f32x4{0.f, 0.f, 0.f, 0.f};

    glds16(Ah_g + gaA, &sAh[0][lb]);
    glds16(Al_g + gaA, &sAl[0][lb]);
    glds16(Wh_g + gaW, &sWh[0][lb]);
    glds16(Wl_g + gaW, &sWl[0][lb]);
    glds16(Ah_g + gaA + 32, &sAh[1][lb]);
    glds16(Al_g + gaA + 32, &sAl[1][lb]);
    glds16(Wh_g + gaW + 32, &sWh[1][lb]);
    glds16(Wl_g + gaW + 32, &sWl[1][lb]);

    int cur = 0;
    for (int s = 0; s < nsteps; ++s) {
      if (s < nsteps - 1) asm volatile("s_waitcnt vmcnt(4)" ::: "memory");
      else                asm volatile("s_waitcnt vmcnt(0)" ::: "memory");
      __builtin_amdgcn_s_barrier();
      __builtin_amdgcn_sched_barrier(0);
      if (s + 2 < nsteps) {
        int nk = (s + 2) * 32;
        int nb = (cur >= 1) ? cur - 1 : 2;
        glds16(Ah_g + gaA + nk, &sAh[nb][lb]);
        glds16(Al_g + gaA + nk, &sAl[nb][lb]);
        glds16(Wh_g + gaW + nk, &sWh[nb][lb]);
        glds16(Wl_g + gaW + nk, &sWl[nb][lb]);
      }
      short8_t ah[2], al[2], wh[2], wl[2];
#pragma unroll
      for (int i = 0; i < 2; ++i) {
        int ra = wm + i * 16 + fr;
        int oa = ra * 32 + ((fg ^ ((ra >> 1) & 3)) << 3);
        ah[i] = *(short8_t*)&sAh[cur][oa];
        al[i] = *(short8_t*)&sAl[cur][oa];
        int rw = wn + i * 16 + fr;
        int ow = rw * 32 + ((fg ^ ((rw >> 1) & 3)) << 3);
        wh[i] = *(short8_t*)&sWh[cur][ow];
        wl[i] = *(short8_t*)&sWl[cur][ow];
      }
#pragma unroll
      for (int i = 0; i < 2; ++i)
#pragma unroll
        for (int j = 0; j < 2; ++j) {
          acc[i][j] = __builtin_amdgcn_mfma_f32_16x16x32_bf16(ah[i], wh[j], acc[i][j], 0, 0, 0);
          acc[i][j] = __builtin_amdgcn_mfma_f32_16x16x32_bf16(ah[i], wl[j], acc[i][j], 0, 0, 0);
          acc[i][j] = __builtin_amdgcn_mfma_f32_16x16x32_bf16(al[i], wh[j], acc[i][j], 0, 0, 0);
        }
      cur = (cur == 2) ? 0 : cur + 1;
    }
    __builtin_amdgcn_s_barrier();
  }

#pragma unroll
  for (int i = 0; i < 2; ++i)
#pragma unroll
    for (int j = 0; j < 2; ++j)
#pragma unroll
      for (int r = 0; r < 4; ++r) {
        int m = row0 + wm + i * 16 + fg * 4 + r;
        int n = col0 + wn + j * 16 + fr;
        float o = acc[i][j][r];
        if (bias) o += bias[n];
        C[(size_t)m * N + n] = o;
      }
}

// ---------------- 32x32 MFMA GEMM, tri-buffered (out_proj), with reps ----------------
__global__ __launch_bounds__(256) void gemm32g_k(const ush* __restrict__ Ah_g,
                                                 const ush* __restrict__ Al_g,
                                                 const ush* __restrict__ Wh_g,
                                                 const ush* __restrict__ Wl_g,
                                                 float* __restrict__ C, int N, int K,
                                                 int reps) {
  __shared__ ush sAh[3][1024], sAl[3][1024], sWh[3][1024], sWl[3][1024];
  const int tid = threadIdx.x, lane = tid & 63, wave = tid >> 6;
  const int ntiles = N / 32;
  const int row0 = (blockIdx.x / ntiles) * 32, col0 = (blockIdx.x % ntiles) * 32;
  const int sr = (wave & 1) * 16 + (lane >> 2);
  const int j8 = ((lane & 3) ^ ((sr >> 1) & 3)) * 8;
  const bool isA = wave < 2;
  const size_t ga = (size_t)((isA ? row0 : col0) + sr) * K + j8;
  const ush* gh = isA ? Ah_g : Wh_g;
  const ush* gl = isA ? Al_g : Wl_g;
  const int lb = (wave & 1) * 512;
  const int nsteps = K >> 5;
  const int fr = lane & 15, fg = lane >> 4;
  const int wrow = wave & 1, wcol = wave >> 1;
  f32x4 acc;

  for (int rp = 0; rp < reps; ++rp) {
    asm volatile("" ::: "memory");
    acc = f32x4{0.f, 0.f, 0.f, 0.f};
    {
      ush* dh0 = isA ? &sAh[0][lb] : &sWh[0][lb];
      ush* dl0 = isA ? &sAl[0][lb] : &sWl[0][lb];
      glds16(gh + ga, dh0);
      glds16(gl + ga, dl0);
      ush* dh1 = isA ? &sAh[1][lb] : &sWh[1][lb];
      ush* dl1 = isA ? &sAl[1][lb] : &sWl[1][lb];
      glds16(gh + ga + 32, dh1);
      glds16(gl + ga + 32, dl1);
    }
    int cur = 0;
    for (int s = 0; s < nsteps; ++s) {
      if (s < nsteps - 1) asm volatile("s_waitcnt vmcnt(2)" ::: "memory");
      else                asm volatile("s_waitcnt vmcnt(0)" ::: "memory");
      __builtin_amdgcn_s_barrier();
      __builtin_amdgcn_sched_barrier(0);
      if (s + 2 < nsteps) {
        int nk = (s + 2) * 32;
        int nb = (cur >= 1) ? cur - 1 : 2;
        ush* dh = isA ? &sAh[nb][lb] : &sWh[nb][lb];
        ush* dl = isA ? &sAl[nb][lb] : &sWl[nb][lb];
        glds16(gh + ga + nk, dh);
        glds16(gl + ga + nk, dl);
      }
      int ra = wrow * 16 + fr;
      int oa = ra * 32 + ((fg ^ ((ra >> 1) & 3)) << 3);
      short8_t ah = *(short8_t*)&sAh[cur][oa];
      short8_t al = *(short8_t*)&sAl[cur][oa];
      int rw = wcol * 16 + fr;
      int ow = rw * 32 + ((fg ^ ((rw >> 1) & 3)) << 3);
      short8_t wh = *(short8_t*)&sWh[cur][ow];
      short8_t wl = *(short8_t*)&sWl[cur][ow];
      acc = __builtin_amdgcn_mfma_f32_16x16x32_bf16(ah, wh, acc, 0, 0, 0);
      acc = __builtin_amdgcn_mfma_f32_16x16x32_bf16(ah, wl, acc, 0, 0, 0);
      acc = __builtin_amdgcn_mfma_f32_16x16x32_bf16(al, wh, acc, 0, 0, 0);
      cur = (cur == 2) ? 0 : cur + 1;
    }
    __builtin_amdgcn_s_barrier();
  }

#pragma unroll
  for (int r = 0; r < 4; ++r) {
    int m = row0 + wrow * 16 + fg * 4 + r;
    int n = col0 + wcol * 16 + fr;
    C[(size_t)m * N + n] = acc[r];
  }
}

// -------- fused residual-add + LayerNorm -> split-bf16, with reps (res write last rep) --
__global__ __launch_bounds__(256) void addlnbf_k(float* __restrict__ res,
                                                 const float* __restrict__ h,
                                                 const float* __restrict__ w,
                                                 const float* __restrict__ b,
                                                 ush* __restrict__ out_h,
                                                 ush* __restrict__ out_l,
                                                 int reps) {
  int n = blockIdx.x * 4 + (threadIdx.x >> 6);
  int t = threadIdx.x & 63;
  for (int rp = 0; rp < reps; ++rp) {
    asm volatile("" ::: "memory");
    float v[3];
    float s = 0.f;
#pragma unroll
    for (int i = 0; i < 3; ++i) {
      int d = t + 64 * i;
      float r = res[(size_t)n * 192 + d] + h[(size_t)n * 192 + d];
      v[i] = r;
      s += r;
    }
#pragma unroll
    for (int off = 32; off >= 1; off >>= 1) s += __shfl_xor(s, off);
    float mu = s * (1.f / 192.f);
    float q = 0.f;
#pragma unroll
    for (int i = 0; i < 3; ++i) { float dd = v[i] - mu; q += dd * dd; }
#pragma unroll
    for (int off = 32; off >= 1; off >>= 1) q += __shfl_xor(q, off);
    float inv = rsqrtf(q * (1.f / 192.f) + EPS);
#pragma unroll
    for (int i = 0; i < 3; ++i) {
      int d = t + 64 * i;
      if (rp == reps - 1) res[(size_t)n * 192 + d] = v[i];
      float o = (v[i] - mu) * inv * w[d] + b[d];
      ush hh = bfh_(o);
      out_h[(size_t)n * 192 + d] = hh;
      out_l[(size_t)n * 192 + d] = bfh_(o - bf2f_(hh));
    }
  }
}

// ---------------- final residual-add + LayerNorm -> fp32 out ----------------
__global__ __launch_bounds__(256) void lnfin_k(const float* __restrict__ res,
                                               const float* __restrict__ h,
                                               const float* __restrict__ w,
                                               const float* __restrict__ b,
                                               float* __restrict__ out) {
  int n = blockIdx.x * 4 + (threadIdx.x >> 6);
  int lane = threadIdx.x & 63;
  if (n >= NROWS) return;
  float v[3];
  float s = 0.f;
#pragma unroll
  for (int i = 0; i < 3; ++i) {
    int d = lane + 64 * i;
    float r = res[(size_t)n * 192 + d] + h[(size_t)n * 192 + d];
    v[i] = r;
    s += r;
  }
#pragma unroll
  for (int off = 32; off >= 1; off >>= 1) s += __shfl_xor(s, off);
  float mu = s * (1.f / 192.f);
  float q = 0.f;
#pragma unroll
  for (int i = 0; i < 3; ++i) { float dd = v[i] - mu; q += dd * dd; }
#pragma unroll
  for (int off = 32; off >= 1; off >>= 1) q += __shfl_xor(q, off);
  float inv = rsqrtf(q * (1.f / 192.f) + EPS);
#pragma unroll
  for (int i = 0; i < 3; ++i) {
    int d = lane + 64 * i;
    out[(size_t)n * 192 + d] = (v[i] - mu) * inv * w[d] + b[d];
  }
}

// -------- conv4+SiLU + x_proj + dt_proj, 4 rows/block; packs scan inputs; reps --------
__global__ __launch_bounds__(384) void conv4_k(const float* __restrict__ xz,
                                               const float* __restrict__ cw,
                                               const float* __restrict__ cb,
                                               const float* __restrict__ xpw,
                                               const float* __restrict__ dtw,
                                               const float* __restrict__ dtb,
                                               const float* __restrict__ dpar,
                                               float* __restrict__ dbl,
                                               float* __restrict__ pk,
                                               int reps) {
  __shared__ __align__(16) float xcl[4][384];
  __shared__ __align__(16) float dbll[4][48];
  const int t = threadIdx.x;
  const int n0 = blockIdx.x * 4;
  const int l0 = n0 % LSEQ;

  for (int rp = 0; rp < reps; ++rp) {
    asm volatile("" ::: "memory");
    float cwv[4];
    *(float4*)cwv = *(const float4*)(cw + t * 4);
    float cbv = cb[t];
#pragma unroll
    for (int r = 0; r < 4; ++r) {
      int l = l0 + r, n = n0 + r;
      float acc = cbv;
#pragma unroll
      for (int k = 0; k < 4; ++k) {
        int ll = l - 3 + k;
        if (ll >= 0) acc += xz[(size_t)(n - 3 + k) * 768 + t] * cwv[k];
      }
      float v = silu_(acc);
      xcl[r][t] = v;
    }
    __syncthreads();

    if (t < 352) {
      const int e = t >> 3, part = t & 7;
      const float4* w4 = (const float4*)(xpw + e * 384 + part * 48);
      const float4* x0 = (const float4*)(&xcl[0][part * 48]);
      const float4* x1 = (const float4*)(&xcl[1][part * 48]);
      const float4* x2 = (const float4*)(&xcl[2][part * 48]);
      const float4* x3 = (const float4*)(&xcl[3][part * 48]);
      float s0 = 0.f, s1 = 0.f, s2 = 0.f, s3 = 0.f;
#pragma unroll
      for (int k = 0; k < 12; ++k) {
        float4 w = w4[k], a;
        a = x0[k]; s0 += a.x * w.x + a.y * w.y + a.z * w.z + a.w * w.w;
        a = x1[k]; s1 += a.x * w.x + a.y * w.y + a.z * w.z + a.w * w.w;
        a = x2[k]; s2 += a.x * w.x + a.y * w.y + a.z * w.z + a.w * w.w;
        a = x3[k]; s3 += a.x * w.x + a.y * w.y + a.z * w.z + a.w * w.w;
      }
#pragma unroll
      for (int off = 1; off <= 4; off <<= 1) {
        s0 += __shfl_xor(s0, off);
        s1 += __shfl_xor(s1, off);
        s2 += __shfl_xor(s2, off);
        s3 += __shfl_xor(s3, off);
      }
      if (part == 0) {
        dbll[0][e] = s0; dbl[(size_t)(n0 + 0) * 44 + e] = s0;
        dbll[1][e] = s1; dbl[(size_t)(n0 + 1) * 44 + e] = s1;
        dbll[2][e] = s2; dbl[(size_t)(n0 + 2) * 44 + e] = s2;
        dbll[3][e] = s3; dbl[(size_t)(n0 + 3) * 44 + e] = s3;
      }
    }
    __syncthreads();

    const float4* dw4 = (const float4*)(dtw + t * 12);
    float4 dw0 = dw4[0], dw1 = dw4[1], dw2 = dw4[2];
    float dtbv = dtb[t];
    float Dp = dpar[t];
#pragma unroll
    for (int r = 0; r < 4; ++r) {
      int n = n0 + r;
      const float4* bb = (const float4*)(&dbll[r][0]);
      float4 b0 = bb[0], b1 = bb[1], b2 = bb[2];
      float a = dtbv
              + dw0.x * b0.x + dw0.y * b0.y + dw0.z * b0.z + dw0.w * b0.w
              + dw1.x * b1.x + dw1.y * b1.y + dw1.z * b1.z + dw1.w * b1.w
              + dw2.x * b2.x + dw2.y * b2.y + dw2.z * b2.z + dw2.w * b2.w;
      float sp = fmaxf(a, 0.f) + log1pf(expf(-fabsf(a)));
      float xcv = xcl[r][t];
      float zv = xz[(size_t)n * 768 + 384 + t];
      float gz = silu_(zv);
      *(float4*)&pk[((size_t)n * 384 + t) * 4] = float4{sp, sp * xcv, Dp * xcv, gz};
    }
    __syncthreads();
  }
}

// ---------------- chunked scan v3: packed inputs, with reps ----------------
__global__ __launch_bounds__(448) void scanF_k(const float* __restrict__ pk,
                                               const float* __restrict__ dbl,
                                               const float* __restrict__ a_log,
                                               ush* __restrict__ y_h,
                                               ush* __restrict__ y_l,
                                               int reps) {
  __shared__ float Pl[4][NCH][20];
  __shared__ float Sl[4][NCH][20];
  const int t = threadIdx.x;
  const int p = t / 112;
  const int r = t - p * 112;
  const int c = r >> 2, e = r & 3;
  const int s4 = e * 4;
  const int bd = blockIdx.x * 4 + p;
  const int b = bd / 384, d = bd - b * 384;
  const int base = b * LSEQ + c * TCH;

  for (int rp = 0; rp < reps; ++rp) {
    asm volatile("" ::: "memory");
    float A[4];
#pragma unroll
    for (int j = 0; j < 4; ++j) A[j] = -expf(a_log[d * 16 + s4 + j]);

    float e_c[TCH], g_c[TCH], q_c[TCH][4];
    float h[4] = {0.f, 0.f, 0.f, 0.f};
    float pr[4] = {1.f, 1.f, 1.f, 1.f};

#pragma unroll
    for (int i = 0; i < TCH; ++i) {
      int n = base + i;
      float4 pkv = *(const float4*)&pk[((size_t)n * 384 + d) * 4];
      float4 Bv = *(const float4*)&dbl[(size_t)n * 44 + 12 + s4];
      float4 Cv = *(const float4*)&dbl[(size_t)n * 44 + 28 + s4];
      float a0 = __expf(pkv.x * A[0]);
      float a1 = __expf(pkv.x * A[1]);
      float a2 = __expf(pkv.x * A[2]);
      float a3 = __expf(pkv.x * A[3]);
      h[0] = a0 * h[0] + pkv.y * Bv.x; pr[0] *= a0;
      h[1] = a1 * h[1] + pkv.y * Bv.y; pr[1] *= a1;
      h[2] = a2 * h[2] + pkv.y * Bv.z; pr[2] *= a2;
      h[3] = a3 * h[3] + pkv.y * Bv.w; pr[3] *= a3;
      float psl = h[0] * Cv.x + h[1] * Cv.y + h[2] * Cv.z + h[3] * Cv.w;
      psl += __shfl_xor(psl, 1);
      psl += __shfl_xor(psl, 2);
      e_c[i] = (psl + pkv.z) * pkv.w;
      g_c[i] = pkv.w;
      q_c[i][0] = pr[0] * Cv.x;
      q_c[i][1] = pr[1] * Cv.y;
      q_c[i][2] = pr[2] * Cv.z;
      q_c[i][3] = pr[3] * Cv.w;
    }
#pragma unroll
    for (int j = 0; j < 4; ++j) {
      Pl[p][c][s4 + j] = pr[j];
      Sl[p][c][s4 + j] = h[j];
    }
    __syncthreads();

#pragma unroll
    for (int off = 1; off < NCH; off <<= 1) {
      float Pp[4], Sp[4];
      if (c >= off) {
#pragma unroll
        for (int j = 0; j < 4; ++j) {
          Pp[j] = Pl[p][c - off][s4 + j];
          Sp[j] = Sl[p][c - off][s4 + j];
        }
      }
      __syncthreads();
      if (c >= off) {
#pragma unroll
        for (int j = 0; j < 4; ++j) {
          float Pc = Pl[p][c][s4 + j], Sc = Sl[p][c][s4 + j];
          Pl[p][c][s4 + j] = Pc * Pp[j];
          Sl[p][c][s4 + j] = Pc * Sp[j] + Sc;
        }
      }
      __syncthreads();
    }

    float h0[4] = {0.f, 0.f, 0.f, 0.f};
    if (c > 0) {
#pragma unroll
      for (int j = 0; j < 4; ++j) h0[j] = Sl[p][c - 1][s4 + j];
    }
#pragma unroll
    for (int i = 0; i < TCH; ++i) {
      float corr = h0[0] * q_c[i][0] + h0[1] * q_c[i][1]
                 + h0[2] * q_c[i][2] + h0[3] * q_c[i][3];
      corr += __shfl_xor(corr, 1);
      corr += __shfl_xor(corr, 2);
      if (e == 0) {
        int n = base + i;
        float o = e_c[i] + corr * g_c[i];
        ush hh = bfh_(o);
        y_h[(size_t)n * 384 + d] = hh;
        y_l[(size_t)n * 384 + d] = bfh_(o - bf2f_(hh));
      }
    }
    __syncthreads();
  }
}

extern "C" void kernel_launch(void* const* d_in, const int* in_sizes, int n_in,
                              void* d_out, int out_size, void* d_ws, size_t ws_size,
                              hipStream_t stream) {
  const float* x        = (const float*)d_in[0];
  const float* patch_w  = (const float*)d_in[1];
  const float* patch_b  = (const float*)d_in[2];
  const float* norm_w   = (const float*)d_in[3];
  const float* norm_b   = (const float*)d_in[4];
  const float* in_proj_w  = (const float*)d_in[5];
  const float* conv_w   = (const float*)d_in[6];
  const float* conv_b   = (const float*)d_in[7];
  const float* x_proj_w = (const float*)d_in[8];
  const float* dt_proj_w = (const float*)d_in[9];
  const float* dt_proj_b = (const float*)d_in[10];
  const float* A_log    = (const float*)d_in[11];
  const float* D_param  = (const float*)d_in[12];
  const float* out_proj_w = (const float*)d_in[13];
  const float* normf_w  = (const float*)d_in[14];
  const float* normf_b  = (const float*)d_in[15];
  float* out = (float*)d_out;
  float* ws = (float*)d_ws;

  // fp32 workspace (float offsets)
  float* res = ws;                     // 301056
  float* xz  = ws + 301056;            // 1600*768 = 1228800
  float* dbl = ws + 1529856;           // 1568*44  = 68992
  float* h   = ws + 1598848;           // 1600*192 = 307200
  float* pk  = ws + 1906048;           // 1568*384*4 = 2408448
  // bf16 area
  ush* ub = (ush*)(ws + 4314496);
  ush* a_h  = ub;                      // 1600*768
  ush* a_l  = ub + 1228800;
  ush* hn_h = ub + 2457600;            // 1600*192
  ush* hn_l = ub + 2764800;
  ush* y_h  = ub + 3072000;            // 1600*384
  ush* y_l  = ub + 3686400;
  ush* pw_h = ub + 4300800;            // 192*768
  ush* pw_l = ub + 4448256;
  ush* ipw_h = ub + 4595712;           // 24*768*192
  ush* ipw_l = ub + 8134656;
  ush* opw_h = ub + 11673600;          // 24*192*384
  ush* opw_l = ub + 13443072;          // end 15212544 ush

  zeros_k<<<294, 256, 0, stream>>>(res, a_h, a_l, hn_h, hn_l, y_h, y_l);
  wsplit3_k<<<(N8_PW + N8_IPW + N8_OPW + 255) / 256, 256, 0, stream>>>(
      patch_w, in_proj_w, out_proj_w, pw_h, pw_l, ipw_h, ipw_l, opw_h, opw_l);
  im2col_k<<<(NROWS * 768 / 8 + 255) / 256, 256, 0, stream>>>(x, a_h, a_l);
  gemm64g_k<<<75, 256, 0, stream>>>(a_h, a_l, pw_h, pw_l, patch_b, h, 192, 768, 1);

  for (int L = 0; L < 24; ++L) {
    // layer 0: each per-layer stage runs 32x for per-stage profiling
    int reps = (L == 0) ? 32 : 1;
    addlnbf_k<<<NROWS / 4, 256, 0, stream>>>(res, h, norm_w + L * 192, norm_b + L * 192,
                                             hn_h, hn_l, reps);
    gemm64g_k<<<300, 256, 0, stream>>>(hn_h, hn_l,
        ipw_h + (size_t)L * 147456, ipw_l + (size_t)L * 147456, nullptr, xz, 768, 192, reps);
    conv4_k<<<NROWS / 4, 384, 0, stream>>>(xz,
        conv_w + (size_t)L * 1536, conv_b + (size_t)L * 384,
        x_proj_w + (size_t)L * 16896,
        dt_proj_w + (size_t)L * 4608, dt_proj_b + (size_t)L * 384,
        D_param + (size_t)L * 384, dbl, pk, reps);
    scanF_k<<<768, 448, 0, stream>>>(pk, dbl,
        A_log + (size_t)L * 6144, y_h, y_l, reps);
    gemm32g_k<<<300, 256, 0, stream>>>(y_h, y_l,
        opw_h + (size_t)L * 73728, opw_l + (size_t)L * 73728, h, 192, 384, reps);
  }

  lnfin_k<<<392, 256, 0, stream>>>(res, h, normf_w, normf_b, out);
}

// Round 18
// 1067.948 us; speedup vs baseline: 2.0023x; 2.0023x over previous
//
#include <hip/hip_runtime.h>

#define NROWS 1568      // BATCH * L = 8 * 196
#define MPAD  1600      // padded rows for GEMM tiles
#define LSEQ  196
#define EPS   1e-5f
#define TCH   7
#define NCH   28

typedef __attribute__((ext_vector_type(8))) short short8_t;   // 8 bf16
typedef __attribute__((ext_vector_type(8))) unsigned short ush8;
typedef __attribute__((ext_vector_type(4))) float f32x4;
typedef unsigned short ush;

__device__ __forceinline__ float silu_(float x) { return x / (1.f + expf(-x)); }
__device__ __forceinline__ float fsilu_(float x) { return x / (1.f + __expf(-x)); }

__device__ __forceinline__ ush bfh_(float f) {
  unsigned u = __float_as_uint(f);
  return (ush)((u + 0x7FFFu + ((u >> 16) & 1u)) >> 16);
}
__device__ __forceinline__ float bf2f_(ush h) {
  return __uint_as_float(((unsigned)h) << 16);
}

// async global->LDS, 16B per lane; LDS dest = wave-uniform base + lane*16
__device__ __forceinline__ void glds16(const ush* g, ush* l) {
  __builtin_amdgcn_global_load_lds(
      (const __attribute__((address_space(1))) void*)g,
      (__attribute__((address_space(3))) void*)l, 16, 0, 0);
}

// ---------------- merged weight split: patch_w | in_proj_w | out_proj_w ----------------
#define N8_PW  18432
#define N8_IPW 442368
#define N8_OPW 221184
__global__ __launch_bounds__(256) void wsplit3_k(const float* __restrict__ pw,
                                                 const float* __restrict__ ipw,
                                                 const float* __restrict__ opw,
                                                 ush* __restrict__ pw_h, ush* __restrict__ pw_l,
                                                 ush* __restrict__ ipw_h, ush* __restrict__ ipw_l,
                                                 ush* __restrict__ opw_h, ush* __restrict__ opw_l) {
  int i = blockIdx.x * 256 + threadIdx.x;
  const float* src;
  ush *hi, *lo;
  size_t off;
  if (i < N8_PW) { src = pw; hi = pw_h; lo = pw_l; off = i; }
  else if (i < N8_PW + N8_IPW) { src = ipw; hi = ipw_h; lo = ipw_l; off = i - N8_PW; }
  else if (i < N8_PW + N8_IPW + N8_OPW) { src = opw; hi = opw_h; lo = opw_l; off = i - N8_PW - N8_IPW; }
  else return;
  float v[8];
  *(float4*)&v[0] = *(const float4*)(src + off * 8);
  *(float4*)&v[4] = *(const float4*)(src + off * 8 + 4);
  ush8 h8, l8;
#pragma unroll
  for (int j = 0; j < 8; ++j) {
    ush h = bfh_(v[j]);
    h8[j] = h;
    l8[j] = bfh_(v[j] - bf2f_(h));
  }
  *(ush8*)&hi[off * 8] = h8;
  *(ush8*)&lo[off * 8] = l8;
}

// ---------------- zero res + pad rows of bf16 activation buffers ----------------
__global__ __launch_bounds__(256) void zeros_k(float* __restrict__ res,
                                               ush* __restrict__ a_h, ush* __restrict__ a_l,
                                               ush* __restrict__ hn_h, ush* __restrict__ hn_l,
                                               ush* __restrict__ y_h, ush* __restrict__ y_l) {
  int i = blockIdx.x * 256 + threadIdx.x;
  ush8 z = {};
  if (i < 75264) ((float4*)res)[i] = float4{0.f, 0.f, 0.f, 0.f};
  if (i < 3072) {
    ((ush8*)(a_h + (size_t)NROWS * 768))[i] = z;
    ((ush8*)(a_l + (size_t)NROWS * 768))[i] = z;
  }
  if (i < 768) {
    ((ush8*)(hn_h + (size_t)NROWS * 192))[i] = z;
    ((ush8*)(hn_l + (size_t)NROWS * 192))[i] = z;
  }
  if (i < 1536) {
    ((ush8*)(y_h + (size_t)NROWS * 384))[i] = z;
    ((ush8*)(y_l + (size_t)NROWS * 384))[i] = z;
  }
}

// ---------------- im2col for patch embedding, bf16 hi/lo out ----------------
__global__ __launch_bounds__(256) void im2col_k(const float* __restrict__ x,
                                                ush* __restrict__ Ah,
                                                ush* __restrict__ Al) {
  int i8 = blockIdx.x * 256 + threadIdx.x;
  if (i8 >= NROWS * 768 / 8) return;
  int idx = i8 * 8;
  int m = idx / 768, r = idx - m * 768;
  int b = m / LSEQ, l = m - b * LSEQ;
  int ph = l / 14, pw = l - ph * 14;
  int c = r >> 8, rem = r & 255, ii = rem >> 4, j = rem & 15;
  const float* src = &x[((b * 3 + c) * 224 + ph * 16 + ii) * 224 + pw * 16 + j];
  float v[8];
  *(float4*)&v[0] = *(const float4*)&src[0];
  *(float4*)&v[4] = *(const float4*)&src[4];
  ush8 h8, l8;
#pragma unroll
  for (int k = 0; k < 8; ++k) {
    ush h = bfh_(v[k]);
    h8[k] = h;
    l8[k] = bfh_(v[k] - bf2f_(h));
  }
  *(ush8*)&Ah[idx] = h8;
  *(ush8*)&Al[idx] = l8;
}

// ---------------- 64x64 MFMA GEMM: tri-buffered glds16 (R13-verified) ----------------
__global__ __launch_bounds__(256) void gemm64g_k(const ush* __restrict__ Ah_g,
                                                 const ush* __restrict__ Al_g,
                                                 const ush* __restrict__ Wh_g,
                                                 const ush* __restrict__ Wl_g,
                                                 const float* __restrict__ bias,
                                                 float* __restrict__ C, int N, int K) {
  __shared__ ush sAh[3][2048], sAl[3][2048], sWh[3][2048], sWl[3][2048];
  const int tid = threadIdx.x, lane = tid & 63, wave = tid >> 6;
  const int ntiles = N / 64;
  const int row0 = (blockIdx.x / ntiles) * 64, col0 = (blockIdx.x % ntiles) * 64;
  const int sr = wave * 16 + (lane >> 2);
  const int j8 = ((lane & 3) ^ ((sr >> 1) & 3)) * 8;
  const size_t gaA = (size_t)(row0 + sr) * K + j8;
  const size_t gaW = (size_t)(col0 + sr) * K + j8;
  const int lb = wave * 512;
  const int nsteps = K >> 5;

  glds16(Ah_g + gaA, &sAh[0][lb]);
  glds16(Al_g + gaA, &sAl[0][lb]);
  glds16(Wh_g + gaW, &sWh[0][lb]);
  glds16(Wl_g + gaW, &sWl[0][lb]);
  glds16(Ah_g + gaA + 32, &sAh[1][lb]);
  glds16(Al_g + gaA + 32, &sAl[1][lb]);
  glds16(Wh_g + gaW + 32, &sWh[1][lb]);
  glds16(Wl_g + gaW + 32, &sWl[1][lb]);

  const int fr = lane & 15, fg = lane >> 4;
  const int wm = (wave & 1) * 32, wn = (wave >> 1) * 32;
  f32x4 acc[2][2] = {};
  int cur = 0;

  for (int s = 0; s < nsteps; ++s) {
    if (s < nsteps - 1) asm volatile("s_waitcnt vmcnt(4)" ::: "memory");
    else                asm volatile("s_waitcnt vmcnt(0)" ::: "memory");
    __builtin_amdgcn_s_barrier();
    __builtin_amdgcn_sched_barrier(0);
    if (s + 2 < nsteps) {
      int nk = (s + 2) * 32;
      int nb = (cur >= 1) ? cur - 1 : 2;
      glds16(Ah_g + gaA + nk, &sAh[nb][lb]);
      glds16(Al_g + gaA + nk, &sAl[nb][lb]);
      glds16(Wh_g + gaW + nk, &sWh[nb][lb]);
      glds16(Wl_g + gaW + nk, &sWl[nb][lb]);
    }
    short8_t ah[2], al[2], wh[2], wl[2];
#pragma unroll
    for (int i = 0; i < 2; ++i) {
      int ra = wm + i * 16 + fr;
      int oa = ra * 32 + ((fg ^ ((ra >> 1) & 3)) << 3);
      ah[i] = *(short8_t*)&sAh[cur][oa];
      al[i] = *(short8_t*)&sAl[cur][oa];
      int rw = wn + i * 16 + fr;
      int ow = rw * 32 + ((fg ^ ((rw >> 1) & 3)) << 3);
      wh[i] = *(short8_t*)&sWh[cur][ow];
      wl[i] = *(short8_t*)&sWl[cur][ow];
    }
#pragma unroll
    for (int i = 0; i < 2; ++i)
#pragma unroll
      for (int j = 0; j < 2; ++j) {
        acc[i][j] = __builtin_amdgcn_mfma_f32_16x16x32_bf16(ah[i], wh[j], acc[i][j], 0, 0, 0);
        acc[i][j] = __builtin_amdgcn_mfma_f32_16x16x32_bf16(ah[i], wl[j], acc[i][j], 0, 0, 0);
        acc[i][j] = __builtin_amdgcn_mfma_f32_16x16x32_bf16(al[i], wh[j], acc[i][j], 0, 0, 0);
      }
    cur = (cur == 2) ? 0 : cur + 1;
  }

#pragma unroll
  for (int i = 0; i < 2; ++i)
#pragma unroll
    for (int j = 0; j < 2; ++j)
#pragma unroll
      for (int r = 0; r < 4; ++r) {
        int m = row0 + wm + i * 16 + fg * 4 + r;
        int n = col0 + wn + j * 16 + fr;
        float o = acc[i][j][r];
        if (bias) o += bias[n];
        C[(size_t)m * N + n] = o;
      }
}

// ---------------- 32x32 MFMA GEMM, tri-buffered (out_proj, R13-verified) ---------------
__global__ __launch_bounds__(256) void gemm32g_k(const ush* __restrict__ Ah_g,
                                                 const ush* __restrict__ Al_g,
                                                 const ush* __restrict__ Wh_g,
                                                 const ush* __restrict__ Wl_g,
                                                 float* __restrict__ C, int N, int K) {
  __shared__ ush sAh[3][1024], sAl[3][1024], sWh[3][1024], sWl[3][1024];
  const int tid = threadIdx.x, lane = tid & 63, wave = tid >> 6;
  const int ntiles = N / 32;
  const int row0 = (blockIdx.x / ntiles) * 32, col0 = (blockIdx.x % ntiles) * 32;
  const int sr = (wave & 1) * 16 + (lane >> 2);
  const int j8 = ((lane & 3) ^ ((sr >> 1) & 3)) * 8;
  const bool isA = wave < 2;
  const size_t ga = (size_t)((isA ? row0 : col0) + sr) * K + j8;
  const ush* gh = isA ? Ah_g : Wh_g;
  const ush* gl = isA ? Al_g : Wl_g;
  const int lb = (wave & 1) * 512;
  const int nsteps = K >> 5;

  {
    ush* dh0 = isA ? &sAh[0][lb] : &sWh[0][lb];
    ush* dl0 = isA ? &sAl[0][lb] : &sWl[0][lb];
    glds16(gh + ga, dh0);
    glds16(gl + ga, dl0);
    ush* dh1 = isA ? &sAh[1][lb] : &sWh[1][lb];
    ush* dl1 = isA ? &sAl[1][lb] : &sWl[1][lb];
    glds16(gh + ga + 32, dh1);
    glds16(gl + ga + 32, dl1);
  }

  const int fr = lane & 15, fg = lane >> 4;
  const int wrow = wave & 1, wcol = wave >> 1;
  f32x4 acc = {};
  int cur = 0;

  for (int s = 0; s < nsteps; ++s) {
    if (s < nsteps - 1) asm volatile("s_waitcnt vmcnt(2)" ::: "memory");
    else                asm volatile("s_waitcnt vmcnt(0)" ::: "memory");
    __builtin_amdgcn_s_barrier();
    __builtin_amdgcn_sched_barrier(0);
    if (s + 2 < nsteps) {
      int nk = (s + 2) * 32;
      int nb = (cur >= 1) ? cur - 1 : 2;
      ush* dh = isA ? &sAh[nb][lb] : &sWh[nb][lb];
      ush* dl = isA ? &sAl[nb][lb] : &sWl[nb][lb];
      glds16(gh + ga + nk, dh);
      glds16(gl + ga + nk, dl);
    }
    int ra = wrow * 16 + fr;
    int oa = ra * 32 + ((fg ^ ((ra >> 1) & 3)) << 3);
    short8_t ah = *(short8_t*)&sAh[cur][oa];
    short8_t al = *(short8_t*)&sAl[cur][oa];
    int rw = wcol * 16 + fr;
    int ow = rw * 32 + ((fg ^ ((rw >> 1) & 3)) << 3);
    short8_t wh = *(short8_t*)&sWh[cur][ow];
    short8_t wl = *(short8_t*)&sWl[cur][ow];
    acc = __builtin_amdgcn_mfma_f32_16x16x32_bf16(ah, wh, acc, 0, 0, 0);
    acc = __builtin_amdgcn_mfma_f32_16x16x32_bf16(ah, wl, acc, 0, 0, 0);
    acc = __builtin_amdgcn_mfma_f32_16x16x32_bf16(al, wh, acc, 0, 0, 0);
    cur = (cur == 2) ? 0 : cur + 1;
  }

#pragma unroll
  for (int r = 0; r < 4; ++r) {
    int m = row0 + wrow * 16 + fg * 4 + r;
    int n = col0 + wcol * 16 + fr;
    C[(size_t)m * N + n] = acc[r];
  }
}

// ---------------- fused residual-add + LayerNorm -> split-bf16 (4 rows/block) ---------
__global__ __launch_bounds__(256) void addlnbf_k(float* __restrict__ res,
                                                 const float* __restrict__ h,
                                                 const float* __restrict__ w,
                                                 const float* __restrict__ b,
                                                 ush* __restrict__ out_h,
                                                 ush* __restrict__ out_l) {
  int n = blockIdx.x * 4 + (threadIdx.x >> 6);
  int t = threadIdx.x & 63;
  float v[3];
  float s = 0.f;
#pragma unroll
  for (int i = 0; i < 3; ++i) {
    int d = t + 64 * i;
    float r = res[(size_t)n * 192 + d] + h[(size_t)n * 192 + d];
    res[(size_t)n * 192 + d] = r;
    v[i] = r;
    s += r;
  }
#pragma unroll
  for (int off = 32; off >= 1; off >>= 1) s += __shfl_xor(s, off);
  float mu = s * (1.f / 192.f);
  float q = 0.f;
#pragma unroll
  for (int i = 0; i < 3; ++i) { float dd = v[i] - mu; q += dd * dd; }
#pragma unroll
  for (int off = 32; off >= 1; off >>= 1) q += __shfl_xor(q, off);
  float inv = rsqrtf(q * (1.f / 192.f) + EPS);
#pragma unroll
  for (int i = 0; i < 3; ++i) {
    int d = t + 64 * i;
    float o = (v[i] - mu) * inv * w[d] + b[d];
    ush hh = bfh_(o);
    out_h[(size_t)n * 192 + d] = hh;
    out_l[(size_t)n * 192 + d] = bfh_(o - bf2f_(hh));
  }
}

// ---------------- final residual-add + LayerNorm -> fp32 out ----------------
__global__ __launch_bounds__(256) void lnfin_k(const float* __restrict__ res,
                                               const float* __restrict__ h,
                                               const float* __restrict__ w,
                                               const float* __restrict__ b,
                                               float* __restrict__ out) {
  int n = blockIdx.x * 4 + (threadIdx.x >> 6);
  int lane = threadIdx.x & 63;
  if (n >= NROWS) return;
  float v[3];
  float s = 0.f;
#pragma unroll
  for (int i = 0; i < 3; ++i) {
    int d = lane + 64 * i;
    float r = res[(size_t)n * 192 + d] + h[(size_t)n * 192 + d];
    v[i] = r;
    s += r;
  }
#pragma unroll
  for (int off = 32; off >= 1; off >>= 1) s += __shfl_xor(s, off);
  float mu = s * (1.f / 192.f);
  float q = 0.f;
#pragma unroll
  for (int i = 0; i < 3; ++i) { float dd = v[i] - mu; q += dd * dd; }
#pragma unroll
  for (int off = 32; off >= 1; off >>= 1) q += __shfl_xor(q, off);
  float inv = rsqrtf(q * (1.f / 192.f) + EPS);
#pragma unroll
  for (int i = 0; i < 3; ++i) {
    int d = lane + 64 * i;
    out[(size_t)n * 192 + d] = (v[i] - mu) * inv * w[d] + b[d];
  }
}

// -------- conv4+SiLU + x_proj + dt_proj, 4 rows/block; packs scan inputs --------
// pk[n][d] = {dt, dt*xc, D*xc, silu(z)}  (float4, coalesced); fast-math exp variants
__global__ __launch_bounds__(384) void conv4_k(const float* __restrict__ xz,
                                               const float* __restrict__ cw,
                                               const float* __restrict__ cb,
                                               const float* __restrict__ xpw,
                                               const float* __restrict__ dtw,
                                               const float* __restrict__ dtb,
                                               const float* __restrict__ dpar,
                                               float* __restrict__ dbl,
                                               float* __restrict__ pk) {
  __shared__ __align__(16) float xcl[4][384];
  __shared__ __align__(16) float dbll[4][48];
  const int t = threadIdx.x;
  const int n0 = blockIdx.x * 4;
  const int l0 = n0 % LSEQ;

  float cwv[4];
  *(float4*)cwv = *(const float4*)(cw + t * 4);
  float cbv = cb[t];
#pragma unroll
  for (int r = 0; r < 4; ++r) {
    int l = l0 + r, n = n0 + r;
    float acc = cbv;
#pragma unroll
    for (int k = 0; k < 4; ++k) {
      int ll = l - 3 + k;
      if (ll >= 0) acc += xz[(size_t)(n - 3 + k) * 768 + t] * cwv[k];
    }
    float v = fsilu_(acc);
    xcl[r][t] = v;
  }
  __syncthreads();

  if (t < 352) {
    const int e = t >> 3, part = t & 7;
    const float4* w4 = (const float4*)(xpw + e * 384 + part * 48);
    const float4* x0 = (const float4*)(&xcl[0][part * 48]);
    const float4* x1 = (const float4*)(&xcl[1][part * 48]);
    const float4* x2 = (const float4*)(&xcl[2][part * 48]);
    const float4* x3 = (const float4*)(&xcl[3][part * 48]);
    float s0 = 0.f, s1 = 0.f, s2 = 0.f, s3 = 0.f;
#pragma unroll
    for (int k = 0; k < 12; ++k) {
      float4 w = w4[k], a;
      a = x0[k]; s0 += a.x * w.x + a.y * w.y + a.z * w.z + a.w * w.w;
      a = x1[k]; s1 += a.x * w.x + a.y * w.y + a.z * w.z + a.w * w.w;
      a = x2[k]; s2 += a.x * w.x + a.y * w.y + a.z * w.z + a.w * w.w;
      a = x3[k]; s3 += a.x * w.x + a.y * w.y + a.z * w.z + a.w * w.w;
    }
#pragma unroll
    for (int off = 1; off <= 4; off <<= 1) {
      s0 += __shfl_xor(s0, off);
      s1 += __shfl_xor(s1, off);
      s2 += __shfl_xor(s2, off);
      s3 += __shfl_xor(s3, off);
    }
    if (part == 0) {
      dbll[0][e] = s0; dbl[(size_t)(n0 + 0) * 44 + e] = s0;
      dbll[1][e] = s1; dbl[(size_t)(n0 + 1) * 44 + e] = s1;
      dbll[2][e] = s2; dbl[(size_t)(n0 + 2) * 44 + e] = s2;
      dbll[3][e] = s3; dbl[(size_t)(n0 + 3) * 44 + e] = s3;
    }
  }
  __syncthreads();

  const float4* dw4 = (const float4*)(dtw + t * 12);
  float4 dw0 = dw4[0], dw1 = dw4[1], dw2 = dw4[2];
  float dtbv = dtb[t];
  float Dp = dpar[t];
#pragma unroll
  for (int r = 0; r < 4; ++r) {
    int n = n0 + r;
    const float4* bb = (const float4*)(&dbll[r][0]);
    float4 b0 = bb[0], b1 = bb[1], b2 = bb[2];
    float a = dtbv
            + dw0.x * b0.x + dw0.y * b0.y + dw0.z * b0.z + dw0.w * b0.w
            + dw1.x * b1.x + dw1.y * b1.y + dw1.z * b1.z + dw1.w * b1.w
            + dw2.x * b2.x + dw2.y * b2.y + dw2.z * b2.z + dw2.w * b2.w;
    float sp = fmaxf(a, 0.f) + __logf(1.f + __expf(-fabsf(a)));
    float xcv = xcl[r][t];
    float zv = xz[(size_t)n * 768 + 384 + t];
    float gz = fsilu_(zv);
    *(float4*)&pk[((size_t)n * 384 + t) * 4] = float4{sp, sp * xcv, Dp * xcv, gz};
  }
}

// -------- chunked scan v4: packed inputs, padded LDS (17), single-wave serial prefix ---
__global__ __launch_bounds__(448) void scanF_k(const float* __restrict__ pk,
                                               const float* __restrict__ dbl,
                                               const float* __restrict__ a_log,
                                               ush* __restrict__ y_h,
                                               ush* __restrict__ y_l) {
  __shared__ float Pl[4][NCH][17];
  __shared__ float Sl[4][NCH][17];
  const int t = threadIdx.x;
  const int p = t / 112;
  const int r = t - p * 112;
  const int c = r >> 2, e = r & 3;
  const int s4 = e * 4;
  const int bd = blockIdx.x * 4 + p;
  const int b = bd / 384, d = bd - b * 384;
  float A[4];
#pragma unroll
  for (int j = 0; j < 4; ++j) A[j] = -expf(a_log[d * 16 + s4 + j]);

  float e_c[TCH], g_c[TCH], q_c[TCH][4];
  float h[4] = {0.f, 0.f, 0.f, 0.f};
  float pr[4] = {1.f, 1.f, 1.f, 1.f};
  const int base = b * LSEQ + c * TCH;

#pragma unroll
  for (int i = 0; i < TCH; ++i) {
    int n = base + i;
    float4 pkv = *(const float4*)&pk[((size_t)n * 384 + d) * 4];  // {dt, u, dxc, gz}
    float4 Bv = *(const float4*)&dbl[(size_t)n * 44 + 12 + s4];
    float4 Cv = *(const float4*)&dbl[(size_t)n * 44 + 28 + s4];
    float a0 = __expf(pkv.x * A[0]);
    float a1 = __expf(pkv.x * A[1]);
    float a2 = __expf(pkv.x * A[2]);
    float a3 = __expf(pkv.x * A[3]);
    h[0] = a0 * h[0] + pkv.y * Bv.x; pr[0] *= a0;
    h[1] = a1 * h[1] + pkv.y * Bv.y; pr[1] *= a1;
    h[2] = a2 * h[2] + pkv.y * Bv.z; pr[2] *= a2;
    h[3] = a3 * h[3] + pkv.y * Bv.w; pr[3] *= a3;
    float psl = h[0] * Cv.x + h[1] * Cv.y + h[2] * Cv.z + h[3] * Cv.w;
    psl += __shfl_xor(psl, 1);
    psl += __shfl_xor(psl, 2);
    e_c[i] = (psl + pkv.z) * pkv.w;
    g_c[i] = pkv.w;
    q_c[i][0] = pr[0] * Cv.x;
    q_c[i][1] = pr[1] * Cv.y;
    q_c[i][2] = pr[2] * Cv.z;
    q_c[i][3] = pr[3] * Cv.w;
  }
#pragma unroll
  for (int j = 0; j < 4; ++j) {
    Pl[p][c][s4 + j] = pr[j];
    Sl[p][c][s4 + j] = h[j];
  }
  __syncthreads();

  // serial affine prefix: 64 independent chains (4 p x 16 states), one per lane of wave 0
  if (t < 64) {
    int pp = t >> 4, ss = t & 15;
    float S_run = Sl[pp][0][ss];
    for (int cc = 1; cc < NCH; ++cc) {
      S_run = Pl[pp][cc][ss] * S_run + Sl[pp][cc][ss];
      Sl[pp][cc][ss] = S_run;
    }
  }
  __syncthreads();

  float h0[4] = {0.f, 0.f, 0.f, 0.f};
  if (c > 0) {
#pragma unroll
    for (int j = 0; j < 4; ++j) h0[j] = Sl[p][c - 1][s4 + j];
  }
#pragma unroll
  for (int i = 0; i < TCH; ++i) {
    float corr = h0[0] * q_c[i][0] + h0[1] * q_c[i][1]
               + h0[2] * q_c[i][2] + h0[3] * q_c[i][3];
    corr += __shfl_xor(corr, 1);
    corr += __shfl_xor(corr, 2);
    if (e == 0) {
      int n = base + i;
      float o = e_c[i] + corr * g_c[i];
      ush hh = bfh_(o);
      y_h[(size_t)n * 384 + d] = hh;
      y_l[(size_t)n * 384 + d] = bfh_(o - bf2f_(hh));
    }
  }
}

extern "C" void kernel_launch(void* const* d_in, const int* in_sizes, int n_in,
                              void* d_out, int out_size, void* d_ws, size_t ws_size,
                              hipStream_t stream) {
  const float* x        = (const float*)d_in[0];
  const float* patch_w  = (const float*)d_in[1];
  const float* patch_b  = (const float*)d_in[2];
  const float* norm_w   = (const float*)d_in[3];
  const float* norm_b   = (const float*)d_in[4];
  const float* in_proj_w  = (const float*)d_in[5];
  const float* conv_w   = (const float*)d_in[6];
  const float* conv_b   = (const float*)d_in[7];
  const float* x_proj_w = (const float*)d_in[8];
  const float* dt_proj_w = (const float*)d_in[9];
  const float* dt_proj_b = (const float*)d_in[10];
  const float* A_log    = (const float*)d_in[11];
  const float* D_param  = (const float*)d_in[12];
  const float* out_proj_w = (const float*)d_in[13];
  const float* normf_w  = (const float*)d_in[14];
  const float* normf_b  = (const float*)d_in[15];
  float* out = (float*)d_out;
  float* ws = (float*)d_ws;

  // fp32 workspace (float offsets)
  float* res = ws;                     // 301056
  float* xz  = ws + 301056;            // 1600*768 = 1228800
  float* dbl = ws + 1529856;           // 1568*44  = 68992
  float* h   = ws + 1598848;           // 1600*192 = 307200
  float* pk  = ws + 1906048;           // 1568*384*4 = 2408448
  // bf16 area
  ush* ub = (ush*)(ws + 4314496);
  ush* a_h  = ub;                      // 1600*768
  ush* a_l  = ub + 1228800;
  ush* hn_h = ub + 2457600;            // 1600*192
  ush* hn_l = ub + 2764800;
  ush* y_h  = ub + 3072000;            // 1600*384
  ush* y_l  = ub + 3686400;
  ush* pw_h = ub + 4300800;            // 192*768
  ush* pw_l = ub + 4448256;
  ush* ipw_h = ub + 4595712;           // 24*768*192
  ush* ipw_l = ub + 8134656;
  ush* opw_h = ub + 11673600;          // 24*192*384
  ush* opw_l = ub + 13443072;          // end 15212544 ush

  zeros_k<<<294, 256, 0, stream>>>(res, a_h, a_l, hn_h, hn_l, y_h, y_l);
  wsplit3_k<<<(N8_PW + N8_IPW + N8_OPW + 255) / 256, 256, 0, stream>>>(
      patch_w, in_proj_w, out_proj_w, pw_h, pw_l, ipw_h, ipw_l, opw_h, opw_l);
  im2col_k<<<(NROWS * 768 / 8 + 255) / 256, 256, 0, stream>>>(x, a_h, a_l);
  gemm64g_k<<<75, 256, 0, stream>>>(a_h, a_l, pw_h, pw_l, patch_b, h, 192, 768);

  for (int L = 0; L < 24; ++L) {
    addlnbf_k<<<NROWS / 4, 256, 0, stream>>>(res, h, norm_w + L * 192, norm_b + L * 192, hn_h, hn_l);
    gemm64g_k<<<300, 256, 0, stream>>>(hn_h, hn_l,
        ipw_h + (size_t)L * 147456, ipw_l + (size_t)L * 147456, nullptr, xz, 768, 192);
    conv4_k<<<NROWS / 4, 384, 0, stream>>>(xz,
        conv_w + (size_t)L * 1536, conv_b + (size_t)L * 384,
        x_proj_w + (size_t)L * 16896,
        dt_proj_w + (size_t)L * 4608, dt_proj_b + (size_t)L * 384,
        D_param + (size_t)L * 384, dbl, pk);
    scanF_k<<<768, 448, 0, stream>>>(pk, dbl,
        A_log + (size_t)L * 6144, y_h, y_l);
    gemm32g_k<<<300, 256, 0, stream>>>(y_h, y_l,
        opw_h + (size_t)L * 73728, opw_l + (size_t)L * 73728, h, 192, 384);
  }

  lnfin_k<<<392, 256, 0, stream>>>(res, h, normf_w, normf_b, out);
}